// Round 6
// baseline (441.039 us; speedup 1.0000x reference)
//
#include <hip/hip_runtime.h>

#define N_NODES 20000
#define N_EDGES 200000
#define HID 128
#define STR 136   // LDS row stride in u16: 272B rows -> every b128 access 16B-aligned
#define NT 3125   // number of 64-edge tiles
#define GPERS 768 // persistent grid (3 blocks/CU @ 52KB LDS)

typedef unsigned short u16;
using bf16x8 = __attribute__((ext_vector_type(8))) __bf16;
using f32x4  = __attribute__((ext_vector_type(4))) float;

__device__ __forceinline__ u16 f2bf(float f) {
  union { float f; unsigned u; } v; v.f = f;
  unsigned u = v.u;
  return (u16)((u + 0x7FFFu + ((u >> 16) & 1u)) >> 16);
}
__device__ __forceinline__ float bf2f(unsigned s) {
  union { unsigned u; float f; } v; v.u = s << 16;
  return v.f;
}
__device__ __forceinline__ bf16x8 ld8(const u16* p) { return *(const bf16x8*)p; }

__device__ __forceinline__ void zero_acc(f32x4 acc[4][2]) {
#pragma unroll
  for (int i = 0; i < 4; ++i) {
    acc[i][0] = (f32x4){0.f, 0.f, 0.f, 0.f};
    acc[i][1] = (f32x4){0.f, 0.f, 0.f, 0.f};
  }
}

// GEMM: D[64 edges][128 ch] += A(edges, via afrag)[64][K] * B(packed W)[K][128].
// Wave w owns n-tiles {2w,2w+1}. Depth-2 explicit B prefetch ring hides L2 latency.
template <int KSTEPS, typename AF>
__device__ __forceinline__ void wgemm(const u16* __restrict__ PW, AF afrag,
                                      f32x4 acc[4][2], int lane, int wave) {
  const u16* pb = PW + (wave * 2 * 64 + lane) * 8;
  bf16x8 b0[2], b1[2];
  b0[0] = ld8(pb);
  b1[0] = ld8(pb + 512);
#pragma unroll
  for (int ks = 0; ks < KSTEPS; ++ks) {
    const int cur = ks & 1, nxt = cur ^ 1;
    if (ks + 1 < KSTEPS) {
      b0[nxt] = ld8(pb + (ks + 1) * 4096);
      b1[nxt] = ld8(pb + (ks + 1) * 4096 + 512);
    }
#pragma unroll
    for (int mt = 0; mt < 4; ++mt) {
      bf16x8 a = afrag(ks, mt);
      acc[mt][0] = __builtin_amdgcn_mfma_f32_16x16x32_bf16(a, b0[cur], acc[mt][0], 0, 0, 0);
      acc[mt][1] = __builtin_amdgcn_mfma_f32_16x16x32_bf16(a, b1[cur], acc[mt][1], 0, 0, 0);
    }
  }
}

// C/D: row(edge) = mt*16 + (lane>>4)*4 + r, col(ch) = wave*32 + nt*16 + (lane&15).
template <bool RELU>
__device__ __forceinline__ void epi_store(u16* buf, const f32x4 acc[4][2],
                                          const float* __restrict__ bias,
                                          int lane, int wave) {
  const int c = lane & 15, q = lane >> 4;
  const float bb0 = bias[wave * 32 + c], bb1 = bias[wave * 32 + 16 + c];
#pragma unroll
  for (int mt = 0; mt < 4; ++mt)
#pragma unroll
    for (int nt = 0; nt < 2; ++nt) {
      const float bb = nt ? bb1 : bb0;
      const int col = wave * 32 + nt * 16 + c;
#pragma unroll
      for (int r = 0; r < 4; ++r) {
        float v = acc[mt][nt][r] + bb;
        if (RELU) v = fmaxf(v, 0.f);
        buf[(mt * 16 + q * 4 + r) * STR + col] = f2bf(v);
      }
    }
}

__device__ __forceinline__ void flush_buf(const u16* buf, u16* __restrict__ gout,
                                          int e0, int tid) {
#pragma unroll
  for (int it = 0; it < 4; ++it) {
    int cid = tid + it * 256, e = cid >> 4, p = cid & 15;
    uint4 v = *(const uint4*)(buf + e * STR + p * 8);
    *(uint4*)(gout + (size_t)(e0 + e) * HID + p * 8) = v;
  }
}

// ---- fold encoder (conv1d+mean) and fuse into M[128x20], C0[128], Wnt[128] ----
__global__ void k_fold(const float* __restrict__ emb, const float* __restrict__ conv_w,
                       const float* __restrict__ conv_b, const float* __restrict__ fuse_w,
                       const float* __restrict__ fuse_b, float* __restrict__ Mt,
                       float* __restrict__ C0, float* __restrict__ Wnt) {
  __shared__ float Ash[128][21];
  int o = threadIdx.x;  // 128 threads
  {
    float b0 = conv_b[o];
#pragma unroll
    for (int p = 0; p < 5; ++p) {
#pragma unroll
      for (int i = 0; i < 8; ++i) {
        float s = 0.f;
#pragma unroll
        for (int k = 0; k < 3; ++k) {
          int t = p + 1 - k;
          if (t >= 0 && t < 5) s += conv_w[(o * 8 + i) * 3 + k];
        }
        s *= 0.2f;
        if (i < 4) Ash[o][p * 4 + i] = s;
        else b0 += emb[p * 4 + (i - 4)] * s;
      }
    }
    Ash[o][20] = b0;
  }
  __syncthreads();
  float m[20];
#pragma unroll
  for (int qq = 0; qq < 20; ++qq) m[qq] = 0.f;
  float c0 = fuse_b[o];
  for (int j = 0; j < 128; ++j) {
    float w = fuse_w[o * 129 + j];
#pragma unroll
    for (int qq = 0; qq < 20; ++qq) m[qq] += w * Ash[j][qq];
    c0 += w * Ash[j][20];
  }
#pragma unroll
  for (int qq = 0; qq < 20; ++qq) Mt[qq * 128 + o] = m[qq];
  C0[o] = c0;
  Wnt[o] = fuse_w[o * 129 + 128];
}

// ---- fold fm_w1 @ g2e_w2 (no relu between them; ea2 unused elsewhere) ----
__global__ void k_fold2(const float* __restrict__ w6, const float* __restrict__ b6,
                        const float* __restrict__ w7, const float* __restrict__ b7,
                        float* __restrict__ W67, float* __restrict__ b67) {
  int o = blockIdx.x;    // 128
  int k = threadIdx.x;   // 128
  float s = 0.f;
  for (int j = 0; j < 128; ++j) s += w7[o * 128 + j] * w6[j * 128 + k];
  W67[o * 128 + k] = s;
  if (k == 0) {
    float sb = 0.f;
    for (int j = 0; j < 128; ++j) sb += w7[o * 128 + j] * b6[j];
    b67[o] = sb + b7[o];
  }
}

// ---- pack weight matrices [128][Kin] into bf16 B-fragment order ----
struct PackArgs {
  const float* src[6];
  u16* dst[6];
  int Kin[6];
  int ksCum[7];
};

__global__ void k_pack(PackArgs pa) {
  int bk = blockIdx.x;
  int mi = 0;
  while (bk >= pa.ksCum[mi + 1]) ++mi;
  int ks = bk - pa.ksCum[mi];
  const float* W = pa.src[mi];
  u16* D = pa.dst[mi] + ks * 4096;
  int Kin = pa.Kin[mi];
#pragma unroll
  for (int t = 0; t < 16; ++t) {
    int el = t * 256 + (int)threadIdx.x;
    int j = el & 7, ln = (el >> 3) & 63, ntile = el >> 9;
    int k = ks * 32 + ((ln >> 4) << 3) + j;
    int n = ntile * 16 + (ln & 15);
    float v = (k < Kin) ? W[n * Kin + k] : 0.0f;
    D[el] = f2bf(v);
  }
}

// ---- node encoder ----
__global__ __launch_bounds__(256) void k_encode(const float* __restrict__ x,
                                                const float* __restrict__ node_type,
                                                const float* __restrict__ Mt,
                                                const float* __restrict__ C0,
                                                const float* __restrict__ Wnt,
                                                u16* __restrict__ h2) {
  __shared__ float xs[2][20];
  int local = threadIdx.x >> 7, o = threadIdx.x & 127;
  int node = blockIdx.x * 2 + local;
  if (threadIdx.x < 40) {
    int nn = threadIdx.x / 20, qq = threadIdx.x % 20;
    xs[nn][qq] = x[(blockIdx.x * 2 + nn) * 20 + qq];
  }
  __syncthreads();
  float acc = C0[o] + Wnt[o] * node_type[node];
#pragma unroll
  for (int qq = 0; qq < 20; ++qq) acc += xs[local][qq] * Mt[qq * 128 + o];
  h2[node * HID + o] = f2bf(acc);
}

// ---- gnn1: persistent, gather-prefetched ----
__global__ __launch_bounds__(256, 3) void k_gnn1(
    const int* __restrict__ eidx, const float* __restrict__ eattr,
    const u16* __restrict__ h2, const u16* __restrict__ pW1, const u16* __restrict__ pW2,
    const u16* __restrict__ pW3, const u16* __restrict__ pW4, const float* __restrict__ b1,
    const float* __restrict__ b2, const float* __restrict__ b3, const float* __restrict__ b4,
    u16* __restrict__ ea1, u16* __restrict__ h3) {
  __shared__ __align__(16) u16 B0[64 * STR], B1[64 * STR], B2[64 * STR];
  const int tid = threadIdx.x, lane = tid & 63, wave = tid >> 6;
  const int m = lane & 15, q = lane >> 4;
  const int aoff = m * STR + q * 8;
  const int* rowI = eidx;
  const int* colI = eidx + N_EDGES;
  const int G = gridDim.x;

  uint4 st[8];
  float4 ea[4];
  int t = blockIdx.x;
  {  // preload tile t
    const int ir = rowI[t * 64 + lane], ic = colI[t * 64 + lane];
    const u16* hr = h2 + (size_t)ir * HID;
    const u16* hc = h2 + (size_t)ic * HID;
#pragma unroll
    for (int it = 0; it < 8; ++it) {
      int g = wave * 8 + it, p = g & 15;
      st[it] = *(const uint4*)((g < 16 ? hr : hc) + p * 8);
    }
    if (q == 0) {
#pragma unroll
      for (int mt = 0; mt < 4; ++mt)
        ea[mt] = *(const float4*)(eattr + (size_t)(t * 64 + mt * 16 + m) * 4);
    }
  }

  f32x4 acc[4][2];
  for (; t < NT; t += G) {
    const int e0 = t * 64;
    const int tc = (t + G < NT) ? (t + G) : t;
    // stage current tile from regs
#pragma unroll
    for (int it = 0; it < 8; ++it) {
      int g = wave * 8 + it, p = g & 15;
      *(uint4*)((g < 16 ? B0 : B1) + lane * STR + p * 8) = st[it];
    }
    bf16x8 ef[4];
#pragma unroll
    for (int mt = 0; mt < 4; ++mt) {
      union { u16 s[8]; uint4 u; bf16x8 v; } tt;
      tt.u = make_uint4(0u, 0u, 0u, 0u);
      if (q == 0) {
        tt.s[0] = f2bf(ea[mt].x); tt.s[1] = f2bf(ea[mt].y);
        tt.s[2] = f2bf(ea[mt].z); tt.s[3] = f2bf(ea[mt].w);
      }
      ef[mt] = tt.v;
    }
    // prefetch next tile's indices (latency covered by GEMM1)
    const int irn = rowI[tc * 64 + lane], icn = colI[tc * 64 + lane];
    __syncthreads();

    zero_acc(acc);  // GEMM1: K=288: [B0 | B1 | eattr-regs]
    wgemm<9>(pW1, [&](int ks, int mt) -> bf16x8 {
      if (ks < 4) return ld8(B0 + aoff + mt * 16 * STR + ks * 32);
      if (ks < 8) return ld8(B1 + aoff + mt * 16 * STR + (ks - 4) * 32);
      return ef[mt];
    }, acc, lane, wave);
    epi_store<true>(B2, acc, b1, lane, wave);  // H -> B2 (untouched in GEMM1)
    // prefetch next eattr
    if (q == 0) {
#pragma unroll
      for (int mt = 0; mt < 4; ++mt)
        ea[mt] = *(const float4*)(eattr + (size_t)(tc * 64 + mt * 16 + m) * 4);
    }
    __syncthreads();

    zero_acc(acc);  // GEMM2: ea1 = W2 x H
    wgemm<4>(pW2, [&](int ks, int mt) -> bf16x8 {
      return ld8(B2 + aoff + mt * 16 * STR + ks * 32);
    }, acc, lane, wave);
    // prefetch next tile's gathers (latency covered by rest of tile)
    {
      const u16* hr = h2 + (size_t)irn * HID;
      const u16* hc = h2 + (size_t)icn * HID;
#pragma unroll
      for (int it = 0; it < 8; ++it) {
        int g = wave * 8 + it, p = g & 15;
        st[it] = *(const uint4*)((g < 16 ? hr : hc) + p * 8);
      }
    }
    epi_store<false>(B1, acc, b2, lane, wave);  // ea1 -> B1 (B1 reads done pre-sync)
    __syncthreads();
    flush_buf(B1, ea1, e0, tid);

    if (e0 < N_NODES) {  // h3 only ever gathered at indices < N
      zero_acc(acc);  // GEMM3: K=256: [B0 h2row | B1 ea1]
      wgemm<8>(pW3, [&](int ks, int mt) -> bf16x8 {
        if (ks < 4) return ld8(B0 + aoff + mt * 16 * STR + ks * 32);
        return ld8(B1 + aoff + mt * 16 * STR + (ks - 4) * 32);
      }, acc, lane, wave);
      epi_store<true>(B2, acc, b3, lane, wave);  // B2 reads (GEMM2) done pre-sync
      __syncthreads();
      zero_acc(acc);  // GEMM4
      wgemm<4>(pW4, [&](int ks, int mt) -> bf16x8 {
        return ld8(B2 + aoff + mt * 16 * STR + ks * 32);
      }, acc, lane, wave);
      epi_store<false>(B0, acc, b4, lane, wave);  // h3 -> B0
      __syncthreads();
      flush_buf(B0, h3, e0, tid);
    }
    __syncthreads();  // flush LDS-reads done before next tile's staging
  }
}

// ---- gnn2 (folded W67) + BN-stats, persistent, gather-prefetched ----
__global__ __launch_bounds__(256, 3) void k_gnn2(
    const int* __restrict__ eidx, const u16* __restrict__ h3, u16* ea1z,
    const u16* __restrict__ pW5, const u16* __restrict__ pW67,
    const float* __restrict__ b5, const float* __restrict__ b67,
    float* __restrict__ partials) {
  __shared__ __align__(16) u16 B0[64 * STR], B1[64 * STR], B2[64 * STR];
  const int tid = threadIdx.x, lane = tid & 63, wave = tid >> 6;
  const int m = lane & 15, q = lane >> 4;
  const int aoff = m * STR + q * 8;
  const int* rowI = eidx;
  const int* colI = eidx + N_EDGES;
  const int G = gridDim.x;

  uint4 st[8], se[4];
  int t = blockIdx.x;
  {  // preload tile t
    const int ir = rowI[t * 64 + lane], ic = colI[t * 64 + lane];
    const u16* hr = h3 + (size_t)ir * HID;
    const u16* hc = h3 + (size_t)ic * HID;
#pragma unroll
    for (int it = 0; it < 8; ++it) {
      int g = wave * 8 + it, p = g & 15;
      st[it] = *(const uint4*)((g < 16 ? hr : hc) + p * 8);
    }
#pragma unroll
    for (int it = 0; it < 4; ++it) {
      int cid = tid + it * 256, e = cid >> 4, p = cid & 15;
      se[it] = *(const uint4*)(ea1z + (size_t)(t * 64 + e) * HID + p * 8);
    }
  }

  float bs0 = 0.f, bq0 = 0.f, bs1 = 0.f, bq1 = 0.f;  // BN running partials
  f32x4 acc[4][2];
  for (; t < NT; t += G) {
    const int e0 = t * 64;
    const int tc = (t + G < NT) ? (t + G) : t;
    // stage current tile from regs
#pragma unroll
    for (int it = 0; it < 8; ++it) {
      int g = wave * 8 + it, p = g & 15;
      *(uint4*)((g < 16 ? B0 : B1) + lane * STR + p * 8) = st[it];
    }
#pragma unroll
    for (int it = 0; it < 4; ++it) {
      int cid = tid + it * 256, e = cid >> 4, p = cid & 15;
      *(uint4*)(B2 + e * STR + p * 8) = se[it];
    }
    const int irn = rowI[tc * 64 + lane], icn = colI[tc * 64 + lane];
    __syncthreads();

    zero_acc(acc);  // GEMM1: K=384: [B0 h3r | B1 h3c | B2 ea1]
    wgemm<12>(pW5, [&](int ks, int mt) -> bf16x8 {
      if (ks < 4) return ld8(B0 + aoff + mt * 16 * STR + ks * 32);
      if (ks < 8) return ld8(B1 + aoff + mt * 16 * STR + (ks - 4) * 32);
      return ld8(B2 + aoff + mt * 16 * STR + (ks - 8) * 32);
    }, acc, lane, wave);
    __syncthreads();  // all B0/B2 reads done before H-epi / z-epi overwrite
    epi_store<true>(B0, acc, b5, lane, wave);  // H -> B0
    // prefetch next tile (covered by GEMM2 + epilogue + flush)
    {
      const u16* hr = h3 + (size_t)irn * HID;
      const u16* hc = h3 + (size_t)icn * HID;
#pragma unroll
      for (int it = 0; it < 8; ++it) {
        int g = wave * 8 + it, p = g & 15;
        st[it] = *(const uint4*)((g < 16 ? hr : hc) + p * 8);
      }
#pragma unroll
      for (int it = 0; it < 4; ++it) {
        int cid = tid + it * 256, e = cid >> 4, p = cid & 15;
        se[it] = *(const uint4*)(ea1z + (size_t)(tc * 64 + e) * HID + p * 8);
      }
    }
    __syncthreads();

    zero_acc(acc);  // GEMM2': z = (fm_w1 @ g2e_w2) @ H + b67
    wgemm<4>(pW67, [&](int ks, int mt) -> bf16x8 {
      return ld8(B0 + aoff + mt * 16 * STR + ks * 32);
    }, acc, lane, wave);
    {  // z epilogue -> B2 + BN accumulation (this wave covers ch wave*32..+31)
      const int c = lane & 15;
      const float bb0 = b67[wave * 32 + c], bb1 = b67[wave * 32 + 16 + c];
#pragma unroll
      for (int mt = 0; mt < 4; ++mt)
#pragma unroll
        for (int r = 0; r < 4; ++r) {
          float v0 = acc[mt][0][r] + bb0;
          float v1 = acc[mt][1][r] + bb1;
          bs0 += v0; bq0 += v0 * v0;
          bs1 += v1; bq1 += v1 * v1;
          int row = mt * 16 + q * 4 + r;
          B2[row * STR + wave * 32 + c] = f2bf(v0);
          B2[row * STR + wave * 32 + 16 + c] = f2bf(v1);
        }
    }
    __syncthreads();
    flush_buf(B2, ea1z, e0, tid);  // z overwrites own ea1 rows (already consumed)
    __syncthreads();               // flush LDS-reads done before next staging
  }

  // write BN partials once per block
  bs0 += __shfl_xor(bs0, 16); bs0 += __shfl_xor(bs0, 32);
  bq0 += __shfl_xor(bq0, 16); bq0 += __shfl_xor(bq0, 32);
  bs1 += __shfl_xor(bs1, 16); bs1 += __shfl_xor(bs1, 32);
  bq1 += __shfl_xor(bq1, 16); bq1 += __shfl_xor(bq1, 32);
  if (lane < 16) {
    int base = (int)blockIdx.x * 256;
    partials[base + wave * 32 + lane] = bs0;
    partials[base + wave * 32 + 16 + lane] = bs1;
    partials[base + 128 + wave * 32 + lane] = bq0;
    partials[base + 128 + wave * 32 + 16 + lane] = bq1;
  }
}

__global__ void k_reduce(const float* __restrict__ partials, float* __restrict__ bnacc,
                         int nrows) {
  int t = threadIdx.x;  // 256
  float s = 0.f;
  for (int b = blockIdx.x; b < nrows; b += 64) s += partials[b * 256 + t];
  atomicAdd(&bnacc[t], s);
}

__global__ void k_bnfin(const float* __restrict__ bnacc, const float* __restrict__ bn_g,
                        const float* __restrict__ bn_b, float* __restrict__ ss) {
  int t = threadIdx.x;  // 128
  float inv = 1.0f / (float)N_EDGES;
  float mu = bnacc[t] * inv;
  float var = bnacc[128 + t] * inv - mu * mu;
  float sc = bn_g[t] * rsqrtf(var + 1e-5f);
  ss[t] = sc;
  ss[128 + t] = bn_b[t] - mu * sc;
}

// ---- head: one edge per thread, streaming ----
__global__ __launch_bounds__(256) void k_head(const u16* __restrict__ z,
                                              const float* __restrict__ ss,
                                              const float* __restrict__ w2,
                                              const float* __restrict__ b2,
                                              float* __restrict__ out) {
  __shared__ float sh_s[128], sh_h[128], sh_w0[128], sh_w1[128], sh_w2[128];
  const int tid = threadIdx.x;
  if (tid < 128) {
    sh_s[tid] = ss[tid];
    sh_h[tid] = ss[128 + tid];
    sh_w0[tid] = w2[tid];
    sh_w1[tid] = w2[128 + tid];
    sh_w2[tid] = w2[256 + tid];
  }
  __syncthreads();
  const int e = blockIdx.x * 256 + tid;
  if (e >= N_EDGES) return;
  float a0 = b2[0], a1 = b2[1], a2 = b2[2];
  const u16* zr = z + (size_t)e * HID;
#pragma unroll
  for (int p = 0; p < 16; ++p) {
    uint4 v = *(const uint4*)(zr + p * 8);
    unsigned wv[4] = {v.x, v.y, v.z, v.w};
#pragma unroll
    for (int k = 0; k < 4; ++k) {
      int ch = p * 8 + k * 2;
      float lo = bf2f(wv[k] & 0xffffu), hi = bf2f(wv[k] >> 16);
      float r0 = fmaxf(fmaf(lo, sh_s[ch], sh_h[ch]), 0.f);
      float r1 = fmaxf(fmaf(hi, sh_s[ch + 1], sh_h[ch + 1]), 0.f);
      a0 += r0 * sh_w0[ch] + r1 * sh_w0[ch + 1];
      a1 += r0 * sh_w1[ch] + r1 * sh_w1[ch + 1];
      a2 += r0 * sh_w2[ch] + r1 * sh_w2[ch + 1];
    }
  }
  out[e * 3 + 0] = a0;
  out[e * 3 + 1] = a1;
  out[e * 3 + 2] = a2;
}

extern "C" void kernel_launch(void* const* d_in, const int* in_sizes, int n_in,
                              void* d_out, int out_size, void* d_ws, size_t ws_size,
                              hipStream_t stream) {
  const float* x         = (const float*)d_in[0];
  const int* eidx        = (const int*)d_in[1];
  const float* eattr     = (const float*)d_in[2];
  const float* node_type = (const float*)d_in[4];
  const float* emb       = (const float*)d_in[5];
  const float* conv_w    = (const float*)d_in[6];
  const float* conv_b    = (const float*)d_in[7];
  const float* fuse_w    = (const float*)d_in[8];
  const float* fuse_b    = (const float*)d_in[9];
  const float* g1e_w1    = (const float*)d_in[10];
  const float* g1e_b1    = (const float*)d_in[11];
  const float* g1e_w2    = (const float*)d_in[12];
  const float* g1e_b2    = (const float*)d_in[13];
  const float* g1n_w1    = (const float*)d_in[14];
  const float* g1n_b1    = (const float*)d_in[15];
  const float* g1n_w2    = (const float*)d_in[16];
  const float* g1n_b2    = (const float*)d_in[17];
  const float* g2e_w1    = (const float*)d_in[18];
  const float* g2e_b1    = (const float*)d_in[19];
  const float* g2e_w2    = (const float*)d_in[20];
  const float* g2e_b2    = (const float*)d_in[21];
  // d_in[22..25] = g2n_* : dead code in the reference (output unused)
  const float* fm_w1     = (const float*)d_in[26];
  const float* fm_b1     = (const float*)d_in[27];
  const float* bn_g      = (const float*)d_in[28];
  const float* bn_b      = (const float*)d_in[29];
  const float* fm_w2     = (const float*)d_in[30];
  const float* fm_b2     = (const float*)d_in[31];
  float* out = (float*)d_out;

  char* ws = (char*)d_ws;
  size_t off = 0;
  auto take = [&](size_t bytes) {
    void* p = ws + off;
    off = (off + bytes + 255) & ~(size_t)255;
    return p;
  };
  u16* h2   = (u16*)take((size_t)N_NODES * HID * 2);
  u16* h3   = (u16*)take((size_t)20032 * HID * 2);  // only rows < N ever gathered
  u16* ea1z = (u16*)take((size_t)N_EDGES * HID * 2);
  float* Mt    = (float*)take(20 * 128 * 4);
  float* C0    = (float*)take(128 * 4);
  float* Wnt   = (float*)take(128 * 4);
  float* bnacc = (float*)take(256 * 4);
  float* bnss  = (float*)take(256 * 4);
  float* W67f  = (float*)take(128 * 128 * 4);
  float* b67   = (float*)take(128 * 4);
  float* partials = (float*)take((size_t)GPERS * 256 * 4);
  u16* pW1  = (u16*)take(9 * 4096 * 2);
  u16* pW2  = (u16*)take(4 * 4096 * 2);
  u16* pW3  = (u16*)take(8 * 4096 * 2);
  u16* pW4  = (u16*)take(4 * 4096 * 2);
  u16* pW5  = (u16*)take(12 * 4096 * 2);
  u16* pW67 = (u16*)take(4 * 4096 * 2);

  hipMemsetAsync(bnacc, 0, 256 * 4, stream);
  k_fold<<<1, 128, 0, stream>>>(emb, conv_w, conv_b, fuse_w, fuse_b, Mt, C0, Wnt);
  k_fold2<<<128, 128, 0, stream>>>(g2e_w2, g2e_b2, fm_w1, fm_b1, W67f, b67);

  PackArgs pa;
  const float* srcs[6] = {g1e_w1, g1e_w2, g1n_w1, g1n_w2, g2e_w1, W67f};
  u16* dsts[6] = {pW1, pW2, pW3, pW4, pW5, pW67};
  int kins[6] = {260, 128, 256, 128, 384, 128};
  int kst[6] = {9, 4, 8, 4, 12, 4};
  int cum = 0;
  for (int i = 0; i < 6; ++i) {
    pa.src[i] = srcs[i]; pa.dst[i] = dsts[i]; pa.Kin[i] = kins[i];
    pa.ksCum[i] = cum; cum += kst[i];
  }
  pa.ksCum[6] = cum;  // 41
  k_pack<<<41, 256, 0, stream>>>(pa);

  k_encode<<<N_NODES / 2, 256, 0, stream>>>(x, node_type, Mt, C0, Wnt, h2);
  k_gnn1<<<GPERS, 256, 0, stream>>>(eidx, eattr, h2, pW1, pW2, pW3, pW4,
                                    g1e_b1, g1e_b2, g1n_b1, g1n_b2, ea1z, h3);
  k_gnn2<<<GPERS, 256, 0, stream>>>(eidx, h3, ea1z, pW5, pW67,
                                    g2e_b1, b67, partials);
  k_reduce<<<64, 256, 0, stream>>>(partials, bnacc, GPERS);
  k_bnfin<<<1, 128, 0, stream>>>(bnacc, bn_g, bn_b, bnss);
  k_head<<<(N_EDGES + 255) / 256, 256, 0, stream>>>(ea1z, bnss, fm_w2, fm_b2, out);
}

// Round 7
// 276.207 us; speedup vs baseline: 1.5968x; 1.5968x over previous
//
#include <hip/hip_runtime.h>

#define N_NODES 20000
#define N_EDGES 200000
#define HID 128
#define STR 136   // LDS row stride in u16: 272B rows -> every b128 access 16B-aligned
#define NBLK 3125 // 64-edge tiles

typedef unsigned short u16;
using bf16x8 = __attribute__((ext_vector_type(8))) __bf16;
using f32x4  = __attribute__((ext_vector_type(4))) float;

__device__ __forceinline__ u16 f2bf(float f) {
  union { float f; unsigned u; } v; v.f = f;
  unsigned u = v.u;
  return (u16)((u + 0x7FFFu + ((u >> 16) & 1u)) >> 16);
}
__device__ __forceinline__ float bf2f(unsigned s) {
  union { unsigned u; float f; } v; v.u = s << 16;
  return v.f;
}
__device__ __forceinline__ bf16x8 ld8(const u16* p) { return *(const bf16x8*)p; }

__device__ __forceinline__ void zero_acc(f32x4 acc[4][2]) {
#pragma unroll
  for (int i = 0; i < 4; ++i) {
    acc[i][0] = (f32x4){0.f, 0.f, 0.f, 0.f};
    acc[i][1] = (f32x4){0.f, 0.f, 0.f, 0.f};
  }
}

// GEMM: D[64 edges][128 ch] += A(edges, via afrag)[64][K] * B(packed W)[K][128].
// Wave w owns n-tiles {2w,2w+1}. Depth-2 explicit B prefetch ring hides L2 latency.
template <int KSTEPS, typename AF>
__device__ __forceinline__ void wgemm(const u16* __restrict__ PW, AF afrag,
                                      f32x4 acc[4][2], int lane, int wave) {
  const u16* pb = PW + (wave * 2 * 64 + lane) * 8;
  bf16x8 b0[2], b1[2];
  b0[0] = ld8(pb);
  b1[0] = ld8(pb + 512);
#pragma unroll
  for (int ks = 0; ks < KSTEPS; ++ks) {
    const int cur = ks & 1, nxt = cur ^ 1;
    if (ks + 1 < KSTEPS) {
      b0[nxt] = ld8(pb + (ks + 1) * 4096);
      b1[nxt] = ld8(pb + (ks + 1) * 4096 + 512);
    }
#pragma unroll
    for (int mt = 0; mt < 4; ++mt) {
      bf16x8 a = afrag(ks, mt);
      acc[mt][0] = __builtin_amdgcn_mfma_f32_16x16x32_bf16(a, b0[cur], acc[mt][0], 0, 0, 0);
      acc[mt][1] = __builtin_amdgcn_mfma_f32_16x16x32_bf16(a, b1[cur], acc[mt][1], 0, 0, 0);
    }
  }
}

// C/D: row(edge) = mt*16 + (lane>>4)*4 + r, col(ch) = wave*32 + nt*16 + (lane&15).
template <bool RELU>
__device__ __forceinline__ void epi_store(u16* buf, const f32x4 acc[4][2],
                                          const float* __restrict__ bias,
                                          int lane, int wave) {
  const int c = lane & 15, q = lane >> 4;
  const float bb0 = bias[wave * 32 + c], bb1 = bias[wave * 32 + 16 + c];
#pragma unroll
  for (int mt = 0; mt < 4; ++mt)
#pragma unroll
    for (int nt = 0; nt < 2; ++nt) {
      const float bb = nt ? bb1 : bb0;
      const int col = wave * 32 + nt * 16 + c;
#pragma unroll
      for (int r = 0; r < 4; ++r) {
        float v = acc[mt][nt][r] + bb;
        if (RELU) v = fmaxf(v, 0.f);
        buf[(mt * 16 + q * 4 + r) * STR + col] = f2bf(v);
      }
    }
}

__device__ __forceinline__ void flush_buf(const u16* buf, u16* __restrict__ gout,
                                          int e0, int tid) {
#pragma unroll
  for (int it = 0; it < 4; ++it) {
    int cid = tid + it * 256, e = cid >> 4, p = cid & 15;
    uint4 v = *(const uint4*)(buf + e * STR + p * 8);
    *(uint4*)(gout + (size_t)(e0 + e) * HID + p * 8) = v;
  }
}

// ---- fold encoder (conv1d+mean) and fuse into M[128x20], C0[128], Wnt[128] ----
__global__ void k_fold(const float* __restrict__ emb, const float* __restrict__ conv_w,
                       const float* __restrict__ conv_b, const float* __restrict__ fuse_w,
                       const float* __restrict__ fuse_b, float* __restrict__ Mt,
                       float* __restrict__ C0, float* __restrict__ Wnt) {
  __shared__ float Ash[128][21];
  int o = threadIdx.x;  // 128 threads
  {
    float b0 = conv_b[o];
#pragma unroll
    for (int p = 0; p < 5; ++p) {
#pragma unroll
      for (int i = 0; i < 8; ++i) {
        float s = 0.f;
#pragma unroll
        for (int k = 0; k < 3; ++k) {
          int t = p + 1 - k;
          if (t >= 0 && t < 5) s += conv_w[(o * 8 + i) * 3 + k];
        }
        s *= 0.2f;
        if (i < 4) Ash[o][p * 4 + i] = s;
        else b0 += emb[p * 4 + (i - 4)] * s;
      }
    }
    Ash[o][20] = b0;
  }
  __syncthreads();
  float m[20];
#pragma unroll
  for (int qq = 0; qq < 20; ++qq) m[qq] = 0.f;
  float c0 = fuse_b[o];
  for (int j = 0; j < 128; ++j) {
    float w = fuse_w[o * 129 + j];
#pragma unroll
    for (int qq = 0; qq < 20; ++qq) m[qq] += w * Ash[j][qq];
    c0 += w * Ash[j][20];
  }
#pragma unroll
  for (int qq = 0; qq < 20; ++qq) Mt[qq * 128 + o] = m[qq];
  C0[o] = c0;
  Wnt[o] = fuse_w[o * 129 + 128];
}

// ---- fold fm_w1 @ g2e_w2 (no relu between them; ea2 unused elsewhere) ----
__global__ void k_fold2(const float* __restrict__ w6, const float* __restrict__ b6,
                        const float* __restrict__ w7, const float* __restrict__ b7,
                        float* __restrict__ W67, float* __restrict__ b67) {
  int o = blockIdx.x;    // 128
  int k = threadIdx.x;   // 128
  float s = 0.f;
  for (int j = 0; j < 128; ++j) s += w7[o * 128 + j] * w6[j * 128 + k];
  W67[o * 128 + k] = s;
  if (k == 0) {
    float sb = 0.f;
    for (int j = 0; j < 128; ++j) sb += w7[o * 128 + j] * b6[j];
    b67[o] = sb + b7[o];
  }
}

// ---- pack weight matrices [128][Kin] into bf16 B-fragment order ----
struct PackArgs {
  const float* src[6];
  u16* dst[6];
  int Kin[6];
  int ksCum[7];
};

__global__ void k_pack(PackArgs pa) {
  int bk = blockIdx.x;
  int mi = 0;
  while (bk >= pa.ksCum[mi + 1]) ++mi;
  int ks = bk - pa.ksCum[mi];
  const float* W = pa.src[mi];
  u16* D = pa.dst[mi] + ks * 4096;
  int Kin = pa.Kin[mi];
#pragma unroll
  for (int t = 0; t < 16; ++t) {
    int el = t * 256 + (int)threadIdx.x;
    int j = el & 7, ln = (el >> 3) & 63, ntile = el >> 9;
    int k = ks * 32 + ((ln >> 4) << 3) + j;
    int n = ntile * 16 + (ln & 15);
    float v = (k < Kin) ? W[n * Kin + k] : 0.0f;
    D[el] = f2bf(v);
  }
}

// ---- node encoder ----
__global__ __launch_bounds__(256) void k_encode(const float* __restrict__ x,
                                                const float* __restrict__ node_type,
                                                const float* __restrict__ Mt,
                                                const float* __restrict__ C0,
                                                const float* __restrict__ Wnt,
                                                u16* __restrict__ h2) {
  __shared__ float xs[2][20];
  int local = threadIdx.x >> 7, o = threadIdx.x & 127;
  int node = blockIdx.x * 2 + local;
  if (threadIdx.x < 40) {
    int nn = threadIdx.x / 20, qq = threadIdx.x % 20;
    xs[nn][qq] = x[(blockIdx.x * 2 + nn) * 20 + qq];
  }
  __syncthreads();
  float acc = C0[o] + Wnt[o] * node_type[node];
#pragma unroll
  for (int qq = 0; qq < 20; ++qq) acc += xs[local][qq] * Mt[qq * 128 + o];
  h2[node * HID + o] = f2bf(acc);
}

// ---- gnn1: 2 LDS buffers -> 4 blocks/CU. ea1 = g1e(h2r,h2c,ea); h3 (blocks<313) ----
__global__ __launch_bounds__(256, 4) void k_gnn1(
    const int* __restrict__ eidx, const float* __restrict__ eattr,
    const u16* __restrict__ h2, const u16* __restrict__ pW1, const u16* __restrict__ pW2,
    const u16* __restrict__ pW3, const u16* __restrict__ pW4, const float* __restrict__ b1,
    const float* __restrict__ b2, const float* __restrict__ b3, const float* __restrict__ b4,
    u16* __restrict__ ea1, u16* __restrict__ h3) {
  __shared__ __align__(16) u16 B0[64 * STR], B1[64 * STR];
  const int tid = threadIdx.x, lane = tid & 63, wave = tid >> 6;
  const int e0 = blockIdx.x * 64;
  const int m = lane & 15, q = lane >> 4;
  const int aoff = m * STR + q * 8;
  const int* rowI = eidx;
  const int* colI = eidx + N_EDGES;
  const int idr = rowI[e0 + lane], idc = colI[e0 + lane];
  const u16* hrow = h2 + (size_t)idr * HID;
  const u16* hcol = h2 + (size_t)idc * HID;

  // stage (transient regs): lane owns edge `lane`; 32 jobs: waves 0,1 -> h2r->B0,
  // waves 2,3 -> h2c->B1.
#pragma unroll
  for (int it = 0; it < 8; ++it) {
    int g = wave * 8 + it;  // 0..31
    int p = g & 15;
    uint4 v = *(const uint4*)((g < 16 ? hrow : hcol) + p * 8);
    *(uint4*)((g < 16 ? B0 : B1) + lane * STR + p * 8) = v;
  }

  // eattr A-frags in registers (K-step 8 of GEMM1)
  bf16x8 ef[4];
#pragma unroll
  for (int mt = 0; mt < 4; ++mt) {
    union { u16 s[8]; uint4 u; bf16x8 v; } t;
    t.u = make_uint4(0u, 0u, 0u, 0u);
    if (q == 0) {
      float4 a = *(const float4*)(eattr + (size_t)(e0 + mt * 16 + m) * 4);
      t.s[0] = f2bf(a.x); t.s[1] = f2bf(a.y); t.s[2] = f2bf(a.z); t.s[3] = f2bf(a.w);
    }
    ef[mt] = t.v;
  }
  __syncthreads();  // S1

  f32x4 acc[4][2];
  zero_acc(acc);  // GEMM1: K=288: [B0 h2r | B1 h2c | eattr-regs]
  wgemm<9>(pW1, [&](int ks, int mt) -> bf16x8 {
    if (ks < 4) return ld8(B0 + aoff + mt * 16 * STR + ks * 32);
    if (ks < 8) return ld8(B1 + aoff + mt * 16 * STR + (ks - 4) * 32);
    return ef[mt];
  }, acc, lane, wave);
  __syncthreads();  // S2: all B0/B1 reads done
  epi_store<true>(B1, acc, b1, lane, wave);  // H -> B1 (h2c dead)
  __syncthreads();  // S3

  zero_acc(acc);  // GEMM2: ea1 = W2 x H
  wgemm<4>(pW2, [&](int ks, int mt) -> bf16x8 {
    return ld8(B1 + aoff + mt * 16 * STR + ks * 32);
  }, acc, lane, wave);
  epi_store<false>(B0, acc, b2, lane, wave);  // ea1 -> B0 (h2r dead since S2)
  __syncthreads();  // S4
  flush_buf(B0, ea1, e0, tid);

  if (e0 < N_NODES) {  // h3 only ever gathered at indices < N
    // re-gather h2row -> B1 (H dead after GEMM2; safe after S4). L2-hit, 313 blocks.
#pragma unroll
    for (int it = 0; it < 4; ++it) {
      int p = wave * 4 + it;  // 0..15
      uint4 v = *(const uint4*)(hrow + p * 8);
      *(uint4*)(B1 + lane * STR + p * 8) = v;
    }
    __syncthreads();  // S5

    zero_acc(acc);  // GEMM3: K=256: [B1 h2row | B0 ea1]
    wgemm<8>(pW3, [&](int ks, int mt) -> bf16x8 {
      if (ks < 4) return ld8(B1 + aoff + mt * 16 * STR + ks * 32);
      return ld8(B0 + aoff + mt * 16 * STR + (ks - 4) * 32);
    }, acc, lane, wave);
    __syncthreads();  // S6: all B0/B1 reads done (flush also long done)
    epi_store<true>(B1, acc, b3, lane, wave);  // H' -> B1
    __syncthreads();  // S7

    zero_acc(acc);  // GEMM4: h3 = W4 x H'
    wgemm<4>(pW4, [&](int ks, int mt) -> bf16x8 {
      return ld8(B1 + aoff + mt * 16 * STR + ks * 32);
    }, acc, lane, wave);
    epi_store<false>(B0, acc, b4, lane, wave);  // h3 -> B0 (ea1 dead since S6)
    __syncthreads();  // S8
    flush_buf(B0, h3, e0, tid);
  }
}

// ---- gnn2 (folded W67) + BN stats: 2 LDS buffers -> 4 blocks/CU ----
__global__ __launch_bounds__(256, 4) void k_gnn2(
    const int* __restrict__ eidx, const u16* __restrict__ h3, u16* ea1z,
    const u16* __restrict__ pW5, const u16* __restrict__ pW67,
    const float* __restrict__ b5, const float* __restrict__ b67,
    float* __restrict__ partials) {
  __shared__ __align__(16) u16 B0[64 * STR], B1[64 * STR];
  const int tid = threadIdx.x, lane = tid & 63, wave = tid >> 6;
  const int e0 = blockIdx.x * 64;
  const int m = lane & 15, q = lane >> 4;
  const int aoff = m * STR + q * 8;
  const int* rowI = eidx;
  const int* colI = eidx + N_EDGES;
  const int idr = rowI[e0 + lane], idc = colI[e0 + lane];
  const u16* hrow = h3 + (size_t)idr * HID;
  const u16* hcol = h3 + (size_t)idc * HID;

#pragma unroll
  for (int it = 0; it < 8; ++it) {
    int g = wave * 8 + it;  // 0..31
    int p = g & 15;
    uint4 v = *(const uint4*)((g < 16 ? hrow : hcol) + p * 8);
    *(uint4*)((g < 16 ? B0 : B1) + lane * STR + p * 8) = v;
  }
  __syncthreads();  // S1

  f32x4 acc[4][2];
  zero_acc(acc);  // GEMM1a: ks 0..7 of K=384: [B0 h3r | B1 h3c]
  wgemm<8>(pW5, [&](int ks, int mt) -> bf16x8 {
    if (ks < 4) return ld8(B0 + aoff + mt * 16 * STR + ks * 32);
    return ld8(B1 + aoff + mt * 16 * STR + (ks - 4) * 32);
  }, acc, lane, wave);
  __syncthreads();  // S2: all B0/B1 reads done

  // stage ea1 (own rows, coalesced) -> B0 (h3r dead)
#pragma unroll
  for (int it = 0; it < 4; ++it) {
    int cid = tid + it * 256, e = cid >> 4, p = cid & 15;
    uint4 v = *(const uint4*)(ea1z + (size_t)(e0 + e) * HID + p * 8);
    *(uint4*)(B0 + e * STR + p * 8) = v;
  }
  __syncthreads();  // S3

  // GEMM1b: ks 8..11 (ea1 part), accumulate into same acc
  wgemm<4>(pW5 + 8 * 4096, [&](int ks, int mt) -> bf16x8 {
    return ld8(B0 + aoff + mt * 16 * STR + ks * 32);
  }, acc, lane, wave);
  epi_store<true>(B1, acc, b5, lane, wave);  // H -> B1 (h3c dead since S2; no reads till S4)
  __syncthreads();  // S4

  zero_acc(acc);  // GEMM2': z = (fm_w1 @ g2e_w2) @ H + b67
  wgemm<4>(pW67, [&](int ks, int mt) -> bf16x8 {
    return ld8(B1 + aoff + mt * 16 * STR + ks * 32);
  }, acc, lane, wave);

  // z epilogue -> B0 + per-channel BN partials (wave covers ch wave*32..+31)
  {
    const int c = lane & 15;
    const float bb0 = b67[wave * 32 + c], bb1 = b67[wave * 32 + 16 + c];
    float s0 = 0.f, q0 = 0.f, s1 = 0.f, q1 = 0.f;
#pragma unroll
    for (int mt = 0; mt < 4; ++mt)
#pragma unroll
      for (int r = 0; r < 4; ++r) {
        float v0 = acc[mt][0][r] + bb0;
        float v1 = acc[mt][1][r] + bb1;
        s0 += v0; q0 += v0 * v0;
        s1 += v1; q1 += v1 * v1;
        int row = mt * 16 + q * 4 + r;
        B0[row * STR + wave * 32 + c] = f2bf(v0);
        B0[row * STR + wave * 32 + 16 + c] = f2bf(v1);
      }
    s0 += __shfl_xor(s0, 16); s0 += __shfl_xor(s0, 32);
    q0 += __shfl_xor(q0, 16); q0 += __shfl_xor(q0, 32);
    s1 += __shfl_xor(s1, 16); s1 += __shfl_xor(s1, 32);
    q1 += __shfl_xor(q1, 16); q1 += __shfl_xor(q1, 32);
    if (lane < 16) {
      int base = (int)blockIdx.x * 256;
      partials[base + wave * 32 + lane] = s0;
      partials[base + wave * 32 + 16 + lane] = s1;
      partials[base + 128 + wave * 32 + lane] = q0;
      partials[base + 128 + wave * 32 + 16 + lane] = q1;
    }
  }
  __syncthreads();  // S5
  flush_buf(B0, ea1z, e0, tid);  // z overwrites own ea1 rows (already consumed)
}

__global__ void k_reduce(const float* __restrict__ partials, float* __restrict__ bnacc,
                         int nrows) {
  int t = threadIdx.x;  // 256
  float s = 0.f;
  for (int b = blockIdx.x; b < nrows; b += 64) s += partials[b * 256 + t];
  atomicAdd(&bnacc[t], s);
}

__global__ void k_bnfin(const float* __restrict__ bnacc, const float* __restrict__ bn_g,
                        const float* __restrict__ bn_b, float* __restrict__ ss) {
  int t = threadIdx.x;  // 128
  float inv = 1.0f / (float)N_EDGES;
  float mu = bnacc[t] * inv;
  float var = bnacc[128 + t] * inv - mu * mu;
  float sc = bn_g[t] * rsqrtf(var + 1e-5f);
  ss[t] = sc;
  ss[128 + t] = bn_b[t] - mu * sc;
}

// ---- head: one edge per thread, streaming ----
__global__ __launch_bounds__(256) void k_head(const u16* __restrict__ z,
                                              const float* __restrict__ ss,
                                              const float* __restrict__ w2,
                                              const float* __restrict__ b2,
                                              float* __restrict__ out) {
  __shared__ float sh_s[128], sh_h[128], sh_w0[128], sh_w1[128], sh_w2[128];
  const int tid = threadIdx.x;
  if (tid < 128) {
    sh_s[tid] = ss[tid];
    sh_h[tid] = ss[128 + tid];
    sh_w0[tid] = w2[tid];
    sh_w1[tid] = w2[128 + tid];
    sh_w2[tid] = w2[256 + tid];
  }
  __syncthreads();
  const int e = blockIdx.x * 256 + tid;
  if (e >= N_EDGES) return;
  float a0 = b2[0], a1 = b2[1], a2 = b2[2];
  const u16* zr = z + (size_t)e * HID;
#pragma unroll
  for (int p = 0; p < 16; ++p) {
    uint4 v = *(const uint4*)(zr + p * 8);
    unsigned wv[4] = {v.x, v.y, v.z, v.w};
#pragma unroll
    for (int k = 0; k < 4; ++k) {
      int ch = p * 8 + k * 2;
      float lo = bf2f(wv[k] & 0xffffu), hi = bf2f(wv[k] >> 16);
      float r0 = fmaxf(fmaf(lo, sh_s[ch], sh_h[ch]), 0.f);
      float r1 = fmaxf(fmaf(hi, sh_s[ch + 1], sh_h[ch + 1]), 0.f);
      a0 += r0 * sh_w0[ch] + r1 * sh_w0[ch + 1];
      a1 += r0 * sh_w1[ch] + r1 * sh_w1[ch + 1];
      a2 += r0 * sh_w2[ch] + r1 * sh_w2[ch + 1];
    }
  }
  out[e * 3 + 0] = a0;
  out[e * 3 + 1] = a1;
  out[e * 3 + 2] = a2;
}

extern "C" void kernel_launch(void* const* d_in, const int* in_sizes, int n_in,
                              void* d_out, int out_size, void* d_ws, size_t ws_size,
                              hipStream_t stream) {
  const float* x         = (const float*)d_in[0];
  const int* eidx        = (const int*)d_in[1];
  const float* eattr     = (const float*)d_in[2];
  const float* node_type = (const float*)d_in[4];
  const float* emb       = (const float*)d_in[5];
  const float* conv_w    = (const float*)d_in[6];
  const float* conv_b    = (const float*)d_in[7];
  const float* fuse_w    = (const float*)d_in[8];
  const float* fuse_b    = (const float*)d_in[9];
  const float* g1e_w1    = (const float*)d_in[10];
  const float* g1e_b1    = (const float*)d_in[11];
  const float* g1e_w2    = (const float*)d_in[12];
  const float* g1e_b2    = (const float*)d_in[13];
  const float* g1n_w1    = (const float*)d_in[14];
  const float* g1n_b1    = (const float*)d_in[15];
  const float* g1n_w2    = (const float*)d_in[16];
  const float* g1n_b2    = (const float*)d_in[17];
  const float* g2e_w1    = (const float*)d_in[18];
  const float* g2e_b1    = (const float*)d_in[19];
  const float* g2e_w2    = (const float*)d_in[20];
  const float* g2e_b2    = (const float*)d_in[21];
  // d_in[22..25] = g2n_* : dead code in the reference (output unused)
  const float* fm_w1     = (const float*)d_in[26];
  const float* fm_b1     = (const float*)d_in[27];
  const float* bn_g      = (const float*)d_in[28];
  const float* bn_b      = (const float*)d_in[29];
  const float* fm_w2     = (const float*)d_in[30];
  const float* fm_b2     = (const float*)d_in[31];
  float* out = (float*)d_out;

  char* ws = (char*)d_ws;
  size_t off = 0;
  auto take = [&](size_t bytes) {
    void* p = ws + off;
    off = (off + bytes + 255) & ~(size_t)255;
    return p;
  };
  u16* h2   = (u16*)take((size_t)N_NODES * HID * 2);
  u16* h3   = (u16*)take((size_t)20032 * HID * 2);  // only rows < N ever gathered
  u16* ea1z = (u16*)take((size_t)N_EDGES * HID * 2);
  float* Mt    = (float*)take(20 * 128 * 4);
  float* C0    = (float*)take(128 * 4);
  float* Wnt   = (float*)take(128 * 4);
  float* bnacc = (float*)take(256 * 4);
  float* bnss  = (float*)take(256 * 4);
  float* W67f  = (float*)take(128 * 128 * 4);
  float* b67   = (float*)take(128 * 4);
  float* partials = (float*)take((size_t)NBLK * 256 * 4);
  u16* pW1  = (u16*)take(9 * 4096 * 2);
  u16* pW2  = (u16*)take(4 * 4096 * 2);
  u16* pW3  = (u16*)take(8 * 4096 * 2);
  u16* pW4  = (u16*)take(4 * 4096 * 2);
  u16* pW5  = (u16*)take(12 * 4096 * 2);
  u16* pW67 = (u16*)take(4 * 4096 * 2);

  hipMemsetAsync(bnacc, 0, 256 * 4, stream);
  k_fold<<<1, 128, 0, stream>>>(emb, conv_w, conv_b, fuse_w, fuse_b, Mt, C0, Wnt);
  k_fold2<<<128, 128, 0, stream>>>(g2e_w2, g2e_b2, fm_w1, fm_b1, W67f, b67);

  PackArgs pa;
  const float* srcs[6] = {g1e_w1, g1e_w2, g1n_w1, g1n_w2, g2e_w1, W67f};
  u16* dsts[6] = {pW1, pW2, pW3, pW4, pW5, pW67};
  int kins[6] = {260, 128, 256, 128, 384, 128};
  int kst[6] = {9, 4, 8, 4, 12, 4};
  int cum = 0;
  for (int i = 0; i < 6; ++i) {
    pa.src[i] = srcs[i]; pa.dst[i] = dsts[i]; pa.Kin[i] = kins[i];
    pa.ksCum[i] = cum; cum += kst[i];
  }
  pa.ksCum[6] = cum;  // 41
  k_pack<<<41, 256, 0, stream>>>(pa);

  k_encode<<<N_NODES / 2, 256, 0, stream>>>(x, node_type, Mt, C0, Wnt, h2);
  k_gnn1<<<NBLK, 256, 0, stream>>>(eidx, eattr, h2, pW1, pW2, pW3, pW4,
                                   g1e_b1, g1e_b2, g1n_b1, g1n_b2, ea1z, h3);
  k_gnn2<<<NBLK, 256, 0, stream>>>(eidx, h3, ea1z, pW5, pW67,
                                   g2e_b1, b67, partials);
  k_reduce<<<64, 256, 0, stream>>>(partials, bnacc, NBLK);
  k_bnfin<<<1, 128, 0, stream>>>(bnacc, bn_g, bn_b, bnss);
  k_head<<<(N_EDGES + 255) / 256, 256, 0, stream>>>(ea1z, bnss, fm_w2, fm_b2, out);
}